// Round 1
// baseline (148.818 us; speedup 1.0000x reference)
//
#include <hip/hip_runtime.h>

#define MIN_NORM 1e-15f
#define MARGIN 9.0f
#define DIM 64
#define B_ROWS 1024
#define NC 1024

__device__ inline float wave_reduce_sum(float v) {
    #pragma unroll
    for (int off = 32; off > 0; off >>= 1) v += __shfl_xor(v, off, 64);
    return v;
}

// One wave (64 lanes) per output row: computes transformed head vector and
// per-row scalars. 4 rows per 256-thread block.
__global__ __launch_bounds__(256) void head_kernel(
    const int* __restrict__ u_idx, const int* __restrict__ r_idx,
    const float* __restrict__ emb, const float* __restrict__ rel_diag,
    const float* __restrict__ rb1, const float* __restrict__ rb2,
    const float* __restrict__ bias_head, const float* __restrict__ sigma,
    float* __restrict__ head_out, float* __restrict__ scal_out)
{
    const int lane = threadIdx.x & 63;
    const int row = blockIdx.x * 4 + (threadIdx.x >> 6);
    if (row >= B_ROWS) return;
    const int u = u_idx[row];
    const int r = r_idx[row];

    // head = expmap0(emb[u])
    float x = emb[(long)u * DIM + lane];
    {
        float n2 = wave_reduce_sum(x * x);
        float un = fmaxf(sqrtf(n2), MIN_NORM);
        x = tanhf(un) / un * x;
    }
    // r_b1 = expmap0(rb1[r])
    float y = rb1[(long)r * DIM + lane];
    {
        float n2 = wave_reduce_sum(y * y);
        float un = fmaxf(sqrtf(n2), MIN_NORM);
        y = tanhf(un) / un * y;
    }
    // head = mobius_add(head, r_b1)
    {
        float x2 = wave_reduce_sum(x * x);
        float y2 = wave_reduce_sum(y * y);
        float xy = wave_reduce_sum(x * y);
        float den = 1.0f + 2.0f * xy + x2 * y2;
        x = ((1.0f + 2.0f * xy + y2) * x + (1.0f - x2) * y) / fmaxf(den, MIN_NORM);
    }
    // head = givens_rotations(rel_diag[r], head)
    {
        float g  = rel_diag[(long)r * DIM + lane];
        float go = __shfl_xor(g, 1, 64);
        float xo = __shfl_xor(x, 1, 64);
        float gn = fmaxf(sqrtf(g * g + go * go), MIN_NORM);
        // even lane (=x0): g0*x0 - g1*x1 = g*x - go*xo
        // odd  lane (=x1): g1*x0 + g0*x1 = g*xo + go*x
        x = ((lane & 1) ? (g * xo + go * x) : (g * x - go * xo)) / gn;
    }
    // r_b2 = expmap0(rb2[r])
    float z = rb2[(long)r * DIM + lane];
    {
        float n2 = wave_reduce_sum(z * z);
        float un = fmaxf(sqrtf(n2), MIN_NORM);
        z = tanhf(un) / un * z;
    }
    // head = mobius_add(head, r_b2)
    {
        float x2 = wave_reduce_sum(x * x);
        float y2 = wave_reduce_sum(z * z);
        float xy = wave_reduce_sum(x * z);
        float den = 1.0f + 2.0f * xy + x2 * y2;
        x = ((1.0f + 2.0f * xy + y2) * x + (1.0f - x2) * z) / fmaxf(den, MIN_NORM);
    }
    float h2 = wave_reduce_sum(x * x);
    head_out[(long)row * DIM + lane] = x;
    if (lane == 0) {
        scal_out[row * 4 + 0] = h2;
        scal_out[row * 4 + 1] = logf(fmaxf(1.0f - h2, MIN_NORM));
        scal_out[row * 4 + 2] = 1.0f / (1.0f + expf(-sigma[r]));
        scal_out[row * 4 + 3] = bias_head[u];
    }
}

// One block per (row b, chunk of 256 candidates). Each thread gathers one
// embedding row (16x float4) and computes both dot products.
__global__ __launch_bounds__(256) void score_kernel(
    const int* __restrict__ v_idx, const float* __restrict__ emb,
    const float* __restrict__ bias_tail,
    const float* __restrict__ head, const float* __restrict__ scal,
    float* __restrict__ out)
{
    const int b = blockIdx.y;
    const int c = blockIdx.x * 256 + threadIdx.x;

    __shared__ float4 sh[DIM / 4];
    __shared__ float ss[4];
    if (threadIdx.x < DIM / 4)
        sh[threadIdx.x] = ((const float4*)(head + (long)b * DIM))[threadIdx.x];
    if (threadIdx.x < 4)
        ss[threadIdx.x] = scal[b * 4 + threadIdx.x];
    __syncthreads();

    const int v = v_idx[(long)b * NC + c];
    const float4* e4 = (const float4*)(emb + (long)v * DIM);

    float dot = 0.0f, e2 = 0.0f;
    #pragma unroll
    for (int k = 0; k < DIM / 4; ++k) {
        float4 e = e4[k];
        float4 h = sh[k];
        dot = fmaf(h.x, e.x, dot);
        dot = fmaf(h.y, e.y, dot);
        dot = fmaf(h.z, e.z, dot);
        dot = fmaf(h.w, e.w, dot);
        e2 = fmaf(e.x, e.x, e2);
        e2 = fmaf(e.y, e.y, e2);
        e2 = fmaf(e.z, e.z, e2);
        e2 = fmaf(e.w, e.w, e2);
    }

    const float h2 = ss[0], ldh = ss[1], sig = ss[2], bh = ss[3];
    const float un = fmaxf(sqrtf(e2), MIN_NORM);
    const float t = tanhf(un);
    const float s = t / un;
    const float t2 = t * t;               // ||tail||^2
    const float num = h2 + t2 - 2.0f * s * dot;   // ||head - tail||^2
    const float dist = logf(fmaxf(num, MIN_NORM))
                     - sig * logf(fmaxf(1.0f - t2, MIN_NORM))
                     - (1.0f - sig) * ldh;
    out[(long)b * NC + c] = MARGIN - dist + bh + bias_tail[v];
}

extern "C" void kernel_launch(void* const* d_in, const int* in_sizes, int n_in,
                              void* d_out, int out_size, void* d_ws, size_t ws_size,
                              hipStream_t stream) {
    const int*   u_idx     = (const int*)d_in[0];
    const int*   r_idx     = (const int*)d_in[1];
    const int*   v_idx     = (const int*)d_in[2];
    const float* emb       = (const float*)d_in[3];
    const float* rel_diag  = (const float*)d_in[4];
    const float* rb1       = (const float*)d_in[5];
    const float* rb2       = (const float*)d_in[6];
    const float* bias_head = (const float*)d_in[7];
    const float* bias_tail = (const float*)d_in[8];
    const float* sigma     = (const float*)d_in[9];

    float* head = (float*)d_ws;                 // 1024*64 floats
    float* scal = head + (long)B_ROWS * DIM;    // 1024*4 floats

    head_kernel<<<B_ROWS / 4, 256, 0, stream>>>(
        u_idx, r_idx, emb, rel_diag, rb1, rb2, bias_head, sigma, head, scal);

    score_kernel<<<dim3(NC / 256, B_ROWS), 256, 0, stream>>>(
        v_idx, emb, bias_tail, head, scal, (float*)d_out);
}

// Round 2
// 139.499 us; speedup vs baseline: 1.0668x; 1.0668x over previous
//
#include <hip/hip_runtime.h>

#define MIN_NORM 1e-15f
#define MARGIN 9.0f
#define DIM 64
#define B_ROWS 1024
#define NC 1024

__device__ inline float wave_reduce_sum(float v) {
    #pragma unroll
    for (int off = 32; off > 0; off >>= 1) v += __shfl_xor(v, off, 64);
    return v;
}

// One wave (64 lanes) per output row: computes transformed head vector and
// per-row scalars. 4 rows per 256-thread block.
__global__ __launch_bounds__(256) void head_kernel(
    const int* __restrict__ u_idx, const int* __restrict__ r_idx,
    const float* __restrict__ emb, const float* __restrict__ rel_diag,
    const float* __restrict__ rb1, const float* __restrict__ rb2,
    const float* __restrict__ bias_head, const float* __restrict__ sigma,
    float* __restrict__ head_out, float* __restrict__ scal_out)
{
    const int lane = threadIdx.x & 63;
    const int row = blockIdx.x * 4 + (threadIdx.x >> 6);
    if (row >= B_ROWS) return;
    const int u = u_idx[row];
    const int r = r_idx[row];

    float x = emb[(long)u * DIM + lane];
    {
        float n2 = wave_reduce_sum(x * x);
        float un = fmaxf(sqrtf(n2), MIN_NORM);
        x = tanhf(un) / un * x;
    }
    float y = rb1[(long)r * DIM + lane];
    {
        float n2 = wave_reduce_sum(y * y);
        float un = fmaxf(sqrtf(n2), MIN_NORM);
        y = tanhf(un) / un * y;
    }
    {
        float x2 = wave_reduce_sum(x * x);
        float y2 = wave_reduce_sum(y * y);
        float xy = wave_reduce_sum(x * y);
        float den = 1.0f + 2.0f * xy + x2 * y2;
        x = ((1.0f + 2.0f * xy + y2) * x + (1.0f - x2) * y) / fmaxf(den, MIN_NORM);
    }
    {
        float g  = rel_diag[(long)r * DIM + lane];
        float go = __shfl_xor(g, 1, 64);
        float xo = __shfl_xor(x, 1, 64);
        float gn = fmaxf(sqrtf(g * g + go * go), MIN_NORM);
        x = ((lane & 1) ? (g * xo + go * x) : (g * x - go * xo)) / gn;
    }
    float z = rb2[(long)r * DIM + lane];
    {
        float n2 = wave_reduce_sum(z * z);
        float un = fmaxf(sqrtf(n2), MIN_NORM);
        z = tanhf(un) / un * z;
    }
    {
        float x2 = wave_reduce_sum(x * x);
        float y2 = wave_reduce_sum(z * z);
        float xy = wave_reduce_sum(x * z);
        float den = 1.0f + 2.0f * xy + x2 * y2;
        x = ((1.0f + 2.0f * xy + y2) * x + (1.0f - x2) * z) / fmaxf(den, MIN_NORM);
    }
    float h2 = wave_reduce_sum(x * x);
    head_out[(long)row * DIM + lane] = x;
    if (lane == 0) {
        scal_out[row * 4 + 0] = h2;
        scal_out[row * 4 + 1] = logf(fmaxf(1.0f - h2, MIN_NORM));
        scal_out[row * 4 + 2] = 1.0f / (1.0f + expf(-sigma[r]));
        scal_out[row * 4 + 3] = bias_head[u];
    }
}

// 4-lane cooperative gather: group of 4 lanes shares one candidate row.
// Each thread: 4 candidates x 4 float4 loads, each instruction covering a
// contiguous 64B line per group (full coalescing). Butterfly-reduce within
// the group; lane `sub` owns candidate j==sub for the epilogue, so stores
// are perfectly coalesced and the epilogue has zero divergence.
__global__ __launch_bounds__(256) void score_kernel(
    const int* __restrict__ v_idx, const float* __restrict__ emb,
    const float* __restrict__ bias_tail,
    const float* __restrict__ head, const float* __restrict__ scal,
    float* __restrict__ out)
{
    const int b = blockIdx.y;
    const int base = blockIdx.x * 256;          // 256 candidates per block
    const int t = threadIdx.x;
    const int g = t >> 2;                        // 64 groups per block
    const int sub = t & 3;

    __shared__ float4 sh[DIM / 4];
    __shared__ float ss[4];
    if (t < DIM / 4)
        sh[t] = ((const float4*)(head + (long)b * DIM))[t];
    if (t < 4)
        ss[t] = scal[b * 4 + t];

    // candidates for this group: base + 4g + {0,1,2,3}
    const int4 v4 = ((const int4*)(v_idx + (long)b * NC + base))[g];
    const int v0 = v4.x, v1 = v4.y, v2 = v4.z, v3 = v4.w;

    __syncthreads();

    // head fragment for this lane: float4 indices 4k+sub
    float4 h[4];
    #pragma unroll
    for (int k = 0; k < 4; ++k) h[k] = sh[4 * k + sub];

    // issue all 16 gather loads (4 candidates x 4 lines), fully coalesced
    float4 e[4][4];
    {
        const float4* p0 = (const float4*)(emb + (long)v0 * DIM);
        const float4* p1 = (const float4*)(emb + (long)v1 * DIM);
        const float4* p2 = (const float4*)(emb + (long)v2 * DIM);
        const float4* p3 = (const float4*)(emb + (long)v3 * DIM);
        #pragma unroll
        for (int k = 0; k < 4; ++k) {
            e[0][k] = p0[4 * k + sub];
            e[1][k] = p1[4 * k + sub];
            e[2][k] = p2[4 * k + sub];
            e[3][k] = p3[4 * k + sub];
        }
    }

    float dot[4], e2[4];
    #pragma unroll
    for (int j = 0; j < 4; ++j) {
        float d = 0.0f, q = 0.0f;
        #pragma unroll
        for (int k = 0; k < 4; ++k) {
            float4 ee = e[j][k];
            float4 hh = h[k];
            d = fmaf(hh.x, ee.x, d); d = fmaf(hh.y, ee.y, d);
            d = fmaf(hh.z, ee.z, d); d = fmaf(hh.w, ee.w, d);
            q = fmaf(ee.x, ee.x, q); q = fmaf(ee.y, ee.y, q);
            q = fmaf(ee.z, ee.z, q); q = fmaf(ee.w, ee.w, q);
        }
        // butterfly within the 4-lane group: all 4 lanes get the full sums
        d += __shfl_xor(d, 1, 64); d += __shfl_xor(d, 2, 64);
        q += __shfl_xor(q, 1, 64); q += __shfl_xor(q, 2, 64);
        dot[j] = d; e2[j] = q;
    }

    // lane `sub` takes candidate j == sub (cndmask chains, no scratch)
    const float D  = (sub == 0) ? dot[0] : (sub == 1) ? dot[1] : (sub == 2) ? dot[2] : dot[3];
    const float E  = (sub == 0) ? e2[0]  : (sub == 1) ? e2[1]  : (sub == 2) ? e2[2]  : e2[3];
    const int myv  = (sub == 0) ? v0     : (sub == 1) ? v1     : (sub == 2) ? v2     : v3;

    const float h2 = ss[0], ldh = ss[1], sig = ss[2], bh = ss[3];
    const float un = fmaxf(sqrtf(E), MIN_NORM);
    const float tn = tanhf(un);
    const float s = tn / un;
    const float t2 = tn * tn;                        // ||tail||^2
    const float num = h2 + t2 - 2.0f * s * D;        // ||head - tail||^2
    const float dist = logf(fmaxf(num, MIN_NORM))
                     - sig * logf(fmaxf(1.0f - t2, MIN_NORM))
                     - (1.0f - sig) * ldh;
    out[(long)b * NC + base + t] = MARGIN - dist + bh + bias_tail[myv];
}

extern "C" void kernel_launch(void* const* d_in, const int* in_sizes, int n_in,
                              void* d_out, int out_size, void* d_ws, size_t ws_size,
                              hipStream_t stream) {
    const int*   u_idx     = (const int*)d_in[0];
    const int*   r_idx     = (const int*)d_in[1];
    const int*   v_idx     = (const int*)d_in[2];
    const float* emb       = (const float*)d_in[3];
    const float* rel_diag  = (const float*)d_in[4];
    const float* rb1       = (const float*)d_in[5];
    const float* rb2       = (const float*)d_in[6];
    const float* bias_head = (const float*)d_in[7];
    const float* bias_tail = (const float*)d_in[8];
    const float* sigma     = (const float*)d_in[9];

    float* head = (float*)d_ws;                 // 1024*64 floats
    float* scal = head + (long)B_ROWS * DIM;    // 1024*4 floats

    head_kernel<<<B_ROWS / 4, 256, 0, stream>>>(
        u_idx, r_idx, emb, rel_diag, rb1, rb2, bias_head, sigma, head, scal);

    score_kernel<<<dim3(NC / 256, B_ROWS), 256, 0, stream>>>(
        v_idx, emb, bias_tail, head, scal, (float*)d_out);
}